// Round 9
// baseline (243.654 us; speedup 1.0000x reference)
//
#include <hip/hip_runtime.h>
#include <hip/hip_bf16.h>
#include <math.h>

// Mamba forward, B=1, L=2048, H=1024, DI=2048, N=16, R=64, K=4
#define H_DIM 1024
#define DI    2048
#define NS    16
#define RR    64
#define LL    2048
#define NC    64   // chunks for the parallel scan
#define CL    32   // chunk length = LL/NC
#define KSPL  16   // split-K factor for x_proj

typedef __bf16 bf16x8 __attribute__((ext_vector_type(8)));
typedef __bf16 bf16x4 __attribute__((ext_vector_type(4)));
typedef float  f32x4  __attribute__((ext_vector_type(4)));

__device__ __forceinline__ float silu_f(float x)  { return x / (1.f + __expf(-x)); }
// Cheap softplus: hw exp/log only (log1pf libm slow path caused acc spills).
__device__ __forceinline__ float softplus_f(float x) {
    const float l = __logf(1.f + __expf(x));
    return x > 15.f ? x : l;
}

__device__ __forceinline__ void gload16(const void* g, void* l) {
    __builtin_amdgcn_global_load_lds(
        (const __attribute__((address_space(1))) void*)g,
        (__attribute__((address_space(3))) void*)l, 16, 0, 0);
}

__device__ __forceinline__ void f2b4(const float* __restrict__ in,
                                     __bf16* __restrict__ out)
{
    float4 v = *(const float4*)in;
    bf16x4 o;
    o[0] = (__bf16)v.x; o[1] = (__bf16)v.y; o[2] = (__bf16)v.z; o[3] = (__bf16)v.w;
    *(bf16x4*)out = o;
}

// XCD-aware chunked swizzle over a 2D grid (requires nwg % 8 == 0).
__device__ __forceinline__ void xcd_swz(int nx, int ny, int& bx, int& by)
{
    const int nwg = nx * ny;
    const int bid = by * nx + bx;
    const int cpx = nwg >> 3;
    const int s   = (bid & 7) * cpx + (bid >> 3);
    bx = s % nx;  by = s / nx;
}

// ---------------------------------------------------------------------------
// One fused conversion kernel: x, in_w, outw, dtw (f2b) + x_proj_w pad.
// ---------------------------------------------------------------------------
#define SEG0 (LL * H_DIM)          // x
#define SEG1 (2 * DI * H_DIM)      // in_w
#define SEG2 (H_DIM * DI)          // outw
#define SEG3 (DI * RR)             // dtw
#define SEG4 (128 * DI)            // xpw_pad
#define CUM0 SEG0
#define CUM1 (CUM0 + SEG1)
#define CUM2 (CUM1 + SEG2)
#define CUM3 (CUM2 + SEG3)
#define CUMT (CUM3 + SEG4)

__global__ __launch_bounds__(256) void convert_all_k(
    const float* __restrict__ x,    const float* __restrict__ in_w,
    const float* __restrict__ outw, const float* __restrict__ dtw,
    const float* __restrict__ xpw,
    __bf16* __restrict__ x_bf,    __bf16* __restrict__ inw_bf,
    __bf16* __restrict__ outw_bf, __bf16* __restrict__ dtw_bf,
    __bf16* __restrict__ xpw_pad)
{
    const int i = (blockIdx.x * 256 + threadIdx.x) * 4;
    if (i < CUM0) {
        f2b4(x + i, x_bf + i);
    } else if (i < CUM1) {
        const int o = i - CUM0;  f2b4(in_w + o, inw_bf + o);
    } else if (i < CUM2) {
        const int o = i - CUM1;  f2b4(outw + o, outw_bf + o);
    } else if (i < CUM3) {
        const int o = i - CUM2;  f2b4(dtw + o, dtw_bf + o);
    } else if (i < CUMT) {
        const int o = i - CUM3;           // over [128][2048]
        const int row = o >> 11;
        if (row < 96) {
            f2b4(xpw + o, xpw_pad + o);
        } else {
            bf16x4 z; z[0] = z[1] = z[2] = z[3] = (__bf16)0.f;
            *(bf16x4*)&xpw_pad[o] = z;
        }
    }
}

// sum the KSPL split-K partials of x_dbl; emit fp32 + bf16
__global__ __launch_bounds__(256) void reduce_xdbl_k(
    const float* __restrict__ part, float* __restrict__ xdbl,
    __bf16* __restrict__ xdbl_bf)
{
    const int idx = blockIdx.x * 256 + threadIdx.x;   // over LL*96
    float s = 0.f;
    #pragma unroll
    for (int z = 0; z < KSPL; ++z) s += part[(size_t)z * (LL * 96) + idx];
    xdbl[idx] = s;
    xdbl_bf[idx] = (__bf16)s;
}

// sum the 2 out_proj split-K partials -> fp32 out (float4 vectorized)
__global__ __launch_bounds__(256) void reduce_out_k(
    const float* __restrict__ part, float* __restrict__ out)
{
    const int i = (blockIdx.x * 256 + threadIdx.x) * 4;   // over LL*H
    f32x4 a = *(const f32x4*)&part[i];
    f32x4 b = *(const f32x4*)&part[(size_t)LL * H_DIM + i];
    *(f32x4*)&out[i] = a + b;
}

// Pipeline waits: counted vmcnt keeps the next stage's loads in flight.
#define WAIT_VM3()  asm volatile("s_waitcnt vmcnt(3)" ::: "memory")
#define WAIT_VM0()  asm volatile("s_waitcnt vmcnt(0)" ::: "memory")

// ---------------------------------------------------------------------------
// in_proj GEMM: 64x128 tile, 3-buffer depth-2 pipeline (counted vmcnt, one
// s_barrier per K-step). grid (32,32) = 1024 blocks (4/CU).
// Writes bf16 xc / res split halves directly.
// ---------------------------------------------------------------------------
__global__ __launch_bounds__(256) void gemm_inproj_k(
    const __bf16* __restrict__ A,        // [L][H]
    const __bf16* __restrict__ W,        // [2DI][H]
    const float* __restrict__ bias,
    __bf16* __restrict__ xc_bf,          // [L][DI]
    __bf16* __restrict__ res_bf)         // [L][DI]
{
    __shared__ __bf16 smA[3][64 * 32];
    __shared__ __bf16 smB[3][128 * 32];
    const int t    = threadIdx.x;
    const int lane = t & 63;
    int bx = blockIdx.x, by = blockIdx.y;
    xcd_swz(32, 32, bx, by);
    const int m0 = by * 64, n0 = bx * 128;
    const int wr = ((t >> 6) >> 1) * 32;
    const int wc = ((t >> 6) & 1) * 64;

    const int srow = t >> 2;
    const int skof = (t & 3) * 8;
    const int lds_base = (t >> 6) * 512;

    const int offA = (wr + (lane & 15)) * 32 + ((lane >> 4) * 8);
    const int offB = (wc + (lane & 15)) * 32 + ((lane >> 4) * 8);

    f32x4 acc[2][4] = {};

#define STAGE_IP(buf, k0)                                                          \
    do {                                                                           \
        gload16(A + (size_t)(m0 + srow)      * H_DIM + (k0) + skof, &smA[buf][lds_base]);        \
        gload16(W + (size_t)(n0 + srow)      * H_DIM + (k0) + skof, &smB[buf][lds_base]);        \
        gload16(W + (size_t)(n0 + 64 + srow) * H_DIM + (k0) + skof, &smB[buf][2048 + lds_base]); \
    } while (0)

    const int nk = H_DIM / 32;            // 32 K-steps
    STAGE_IP(0, 0);
    STAGE_IP(1, 32);
    for (int ks = 0; ks < nk; ++ks) {
        if (ks + 1 < nk) WAIT_VM3(); else WAIT_VM0();
        __builtin_amdgcn_s_barrier();     // tile ks ready; prev reads done
        if (ks + 2 < nk) STAGE_IP((ks + 2) % 3, (ks + 2) * 32);
        const int cb = ks % 3;

        bf16x8 af[2], bfr[4];
        #pragma unroll
        for (int m = 0; m < 2; ++m) af[m]  = *(const bf16x8*)&smA[cb][offA + m * 512];
        #pragma unroll
        for (int n = 0; n < 4; ++n) bfr[n] = *(const bf16x8*)&smB[cb][offB + n * 512];
        #pragma unroll
        for (int m = 0; m < 2; ++m)
            #pragma unroll
            for (int n = 0; n < 4; ++n)
                acc[m][n] = __builtin_amdgcn_mfma_f32_16x16x32_bf16(
                    af[m], bfr[n], acc[m][n], 0, 0, 0);
    }
#undef STAGE_IP

    // entire block's col range is on one side of DI (n0 is 128-aligned)
    __bf16* outp = (n0 < DI) ? xc_bf : res_bf;
    const int ncol0 = (n0 < DI) ? n0 : n0 - DI;
    const int rbase = m0 + wr + ((lane >> 4) << 2);
    const int cbase = ncol0 + wc + (lane & 15);
    #pragma unroll
    for (int n = 0; n < 4; ++n) {
        const int col = cbase + n * 16;
        const float bv = bias[(n0 < DI ? 0 : DI) + col];
        #pragma unroll
        for (int m = 0; m < 2; ++m)
            #pragma unroll
            for (int j = 0; j < 4; ++j)
                outp[(size_t)(rbase + m * 16 + j) * DI + col] =
                    (__bf16)(acc[m][n][j] + bv);
    }
}

// ---------------------------------------------------------------------------
// bf16 MFMA GEMM, 64x128 tile, 3-buffer depth-2 pipeline (out_proj / dt_proj
// / x_proj splitK). grid = (N/128, M/64, SPLITK). ncols guards C writes.
// ---------------------------------------------------------------------------
template<int BIAS, int ACT, int SPLITK, int SWZ>
__global__ __launch_bounds__(256) void gemm64_bf16_nt(
    const __bf16* __restrict__ A, int lda,
    const __bf16* __restrict__ W, int ldw,
    const float* __restrict__ bias,
    float* __restrict__ C, int ldc, int ncols, size_t pstride,
    int K)
{
    __shared__ __bf16 smA[3][64 * 32];
    __shared__ __bf16 smB[3][128 * 32];
    const int t    = threadIdx.x;
    const int lane = t & 63;
    int bx = blockIdx.x, by = blockIdx.y;
    if (SWZ) xcd_swz(gridDim.x, gridDim.y, bx, by);
    const int m0 = by * 64, n0 = bx * 128;
    const int wr = ((t >> 6) >> 1) * 32;
    const int wc = ((t >> 6) & 1) * 64;

    const int srow = t >> 2;
    const int skof = (t & 3) * 8;
    const int lds_base = (t >> 6) * 512;

    const int offA = (wr + (lane & 15)) * 32 + ((lane >> 4) * 8);
    const int offB = (wc + (lane & 15)) * 32 + ((lane >> 4) * 8);

    const int kseg  = K / SPLITK;
    const int kbase = (SPLITK > 1) ? blockIdx.z * kseg : 0;

    f32x4 acc[2][4] = {};

#define STAGE_64(buf, k0)                                                          \
    do {                                                                           \
        gload16(A + (size_t)(m0 + srow)      * lda + (k0) + skof, &smA[buf][lds_base]);        \
        gload16(W + (size_t)(n0 + srow)      * ldw + (k0) + skof, &smB[buf][lds_base]);        \
        gload16(W + (size_t)(n0 + 64 + srow) * ldw + (k0) + skof, &smB[buf][2048 + lds_base]); \
    } while (0)

    const int nk = kseg / 32;
    STAGE_64(0, kbase);
    if (nk > 1) STAGE_64(1, kbase + 32);
    for (int ks = 0; ks < nk; ++ks) {
        if (ks + 1 < nk) WAIT_VM3(); else WAIT_VM0();
        __builtin_amdgcn_s_barrier();
        if (ks + 2 < nk) STAGE_64((ks + 2) % 3, kbase + (ks + 2) * 32);
        const int cb = ks % 3;

        bf16x8 af[2], bfr[4];
        #pragma unroll
        for (int m = 0; m < 2; ++m) af[m]  = *(const bf16x8*)&smA[cb][offA + m * 512];
        #pragma unroll
        for (int n = 0; n < 4; ++n) bfr[n] = *(const bf16x8*)&smB[cb][offB + n * 512];
        #pragma unroll
        for (int m = 0; m < 2; ++m)
            #pragma unroll
            for (int n = 0; n < 4; ++n)
                acc[m][n] = __builtin_amdgcn_mfma_f32_16x16x32_bf16(
                    af[m], bfr[n], acc[m][n], 0, 0, 0);
    }
#undef STAGE_64

    float* Cp = C + ((SPLITK > 1) ? (size_t)blockIdx.z * pstride : 0);
    const int rbase = m0 + wr + ((lane >> 4) << 2);
    const int cbase = n0 + wc + (lane & 15);
    #pragma unroll
    for (int n = 0; n < 4; ++n) {
        const int col = cbase + n * 16;
        if (col >= ncols) continue;
        const float bv = BIAS ? bias[col] : 0.f;
        #pragma unroll
        for (int m = 0; m < 2; ++m) {
            #pragma unroll
            for (int j = 0; j < 4; ++j) {
                float v = acc[m][n][j] + bv;
                if (ACT == 1) v = softplus_f(v);
                Cp[(size_t)(rbase + m * 16 + j) * ldc + col] = v;
            }
        }
    }
}

// ---------------------------------------------------------------------------
// Causal depthwise conv (K=4) + bias + silu on bf16 xc; 8 channels/thread.
// ---------------------------------------------------------------------------
__global__ __launch_bounds__(256) void conv_silu_k(
    const __bf16* __restrict__ xc, const float* __restrict__ cw,
    const float* __restrict__ cb, __bf16* __restrict__ xs_bf)
{
    const int idx = blockIdx.x * 256 + threadIdx.x;   // over L*DI/8
    const int l  = idx >> 8;
    const int d0 = (idx & 255) * 8;

    float r0[8] = {}, r1[8] = {}, r2[8] = {}, r3[8];
    bf16x8 v;
    if (l >= 3) { v = *(const bf16x8*)&xc[(size_t)(l-3)*DI + d0];
                  #pragma unroll
                  for (int j = 0; j < 8; ++j) r0[j] = (float)v[j]; }
    if (l >= 2) { v = *(const bf16x8*)&xc[(size_t)(l-2)*DI + d0];
                  #pragma unroll
                  for (int j = 0; j < 8; ++j) r1[j] = (float)v[j]; }
    if (l >= 1) { v = *(const bf16x8*)&xc[(size_t)(l-1)*DI + d0];
                  #pragma unroll
                  for (int j = 0; j < 8; ++j) r2[j] = (float)v[j]; }
    v = *(const bf16x8*)&xc[(size_t)l*DI + d0];
    #pragma unroll
    for (int j = 0; j < 8; ++j) r3[j] = (float)v[j];

    bf16x8 o;
    #pragma unroll
    for (int j = 0; j < 8; ++j) {
        const int d = d0 + j;
        float4 w = *(const float4*)&cw[d * 4];
        float a = cb[d];
        a = fmaf(r0[j], w.x, a);
        a = fmaf(r1[j], w.y, a);
        a = fmaf(r2[j], w.z, a);
        a = fmaf(r3[j], w.w, a);
        o[j] = (__bf16)silu_f(a);
    }
    *(bf16x8*)&xs_bf[(size_t)l*DI + d0] = o;
}

// ---------------------------------------------------------------------------
// Scan phase 1: per-(chunk, channel) local scan, h=0 start.
// ---------------------------------------------------------------------------
__global__ __launch_bounds__(256) void scan1_k(
    const float* __restrict__ delta, const __bf16* __restrict__ xs,
    const float* __restrict__ A_log, const float* __restrict__ xdbl,
    float* __restrict__ P, float* __restrict__ S)
{
    const int d = blockIdx.x * 256 + threadIdx.x;
    const int c = blockIdx.y;
    float A[NS];
    #pragma unroll
    for (int n = 0; n < NS; ++n) A[n] = -__expf(A_log[d * NS + n]);
    float h[NS] = {};
    float ap[NS];
    #pragma unroll
    for (int n = 0; n < NS; ++n) ap[n] = 1.f;

    const int l0 = c * CL;
    for (int l = l0; l < l0 + CL; ++l) {
        const float dt = delta[(size_t)l * DI + d];
        const float u  = (float)xs[(size_t)l * DI + d];
        const float du = dt * u;
        #pragma unroll
        for (int n = 0; n < NS; ++n) {
            const float Bn = xdbl[(size_t)l * 96 + RR + n];
            const float dA = __expf(dt * A[n]);
            h[n]  = fmaf(dA, h[n], du * Bn);
            ap[n] *= dA;
        }
    }
    const size_t base = ((size_t)c * DI + d) * NS;
    #pragma unroll
    for (int n = 0; n < NS; ++n) { P[base + n] = ap[n]; S[base + n] = h[n]; }
}

// ---------------------------------------------------------------------------
// Scan phase 2: sequential over NC chunks; exclusive prefix per (d,n).
// ---------------------------------------------------------------------------
__global__ __launch_bounds__(256) void scan2_k(
    const float* __restrict__ P, const float* __restrict__ S, float* __restrict__ Hp)
{
    const int idx = blockIdx.x * 256 + threadIdx.x;
    float h = 0.f;
    for (int c = 0; c < NC; ++c) {
        const size_t o = (size_t)c * DI * NS + idx;
        Hp[o] = h;
        h = fmaf(P[o], h, S[o]);
    }
}

// ---------------------------------------------------------------------------
// Scan phase 3: replay with prefix, y = (h.C + xs*D)*silu(res), write bf16.
// ---------------------------------------------------------------------------
__global__ __launch_bounds__(256) void scan3_k(
    const float* __restrict__ delta, const __bf16* __restrict__ xs,
    const float* __restrict__ A_log, const float* __restrict__ xdbl,
    const float* __restrict__ Hp, const __bf16* __restrict__ res_bf,
    const float* __restrict__ Dp, __bf16* __restrict__ y_bf)
{
    const int d = blockIdx.x * 256 + threadIdx.x;
    const int c = blockIdx.y;
    float A[NS];
    #pragma unroll
    for (int n = 0; n < NS; ++n) A[n] = -__expf(A_log[d * NS + n]);
    float h[NS];
    const size_t base = ((size_t)c * DI + d) * NS;
    #pragma unroll
    for (int n = 0; n < NS; ++n) h[n] = Hp[base + n];
    const float Dd = Dp[d];

    const int l0 = c * CL;
    for (int l = l0; l < l0 + CL; ++l) {
        const float dt = delta[(size_t)l * DI + d];
        const float u  = (float)xs[(size_t)l * DI + d];
        const float du = dt * u;
        float acc = 0.f;
        #pragma unroll
        for (int n = 0; n < NS; ++n) {
            const float Bn = xdbl[(size_t)l * 96 + RR + n];
            const float Cn = xdbl[(size_t)l * 96 + RR + NS + n];
            const float dA = __expf(dt * A[n]);
            h[n] = fmaf(dA, h[n], du * Bn);
            acc  = fmaf(h[n], Cn, acc);
        }
        float yv = fmaf(u, Dd, acc);
        const float r = (float)res_bf[(size_t)l * DI + d];
        yv *= silu_f(r);
        y_bf[(size_t)l * DI + d] = (__bf16)yv;
    }
}

// ---------------------------------------------------------------------------
extern "C" void kernel_launch(void* const* d_in, const int* in_sizes, int n_in,
                              void* d_out, int out_size, void* d_ws, size_t ws_size,
                              hipStream_t stream)
{
    const float* x        = (const float*)d_in[0];   // [L][H]
    const float* in_w     = (const float*)d_in[1];   // [2DI][H]
    const float* in_b     = (const float*)d_in[2];   // [2DI]
    const float* conv_w   = (const float*)d_in[3];   // [DI][1][4]
    const float* conv_b   = (const float*)d_in[4];   // [DI]
    const float* xproj_w  = (const float*)d_in[5];   // [96][DI]
    const float* dtproj_w = (const float*)d_in[6];   // [DI][R]
    const float* dtproj_b = (const float*)d_in[7];   // [DI]
    const float* A_log    = (const float*)d_in[8];   // [DI][N]
    const float* Dp       = (const float*)d_in[9];   // [DI]
    const float* outw     = (const float*)d_in[10];  // [H][DI]
    float* out = (float*)d_out;                      // [L][H]

    // fp32 workspace
    float* ws    = (float*)d_ws;
    float* delta = ws;                                 // [L][DI] 16MB (splitK partials alias)
    float* xdbl  = delta + (size_t)LL * DI;            // [L][96]
    float* P     = xdbl  + (size_t)LL * 96;            // [NC][DI][NS] 8MB
    float* S     = P     + (size_t)NC * DI * NS;       // 8MB
    float* Hp    = S     + (size_t)NC * DI * NS;       // 8MB
    float* opart = Hp    + (size_t)NC * DI * NS;       // [2][L][H] 16MB
    float* xpart = delta;                              // [KSPL][L][96] = 12.6MB < 16MB
    // bf16 workspace
    __bf16* x_bf    = (__bf16*)(opart + (size_t)2 * LL * H_DIM);
    __bf16* inw_bf  = x_bf    + (size_t)LL * H_DIM;       // [2DI][H]
    __bf16* outw_bf = inw_bf  + (size_t)2 * DI * H_DIM;   // [H][DI]
    __bf16* dtw_bf  = outw_bf + (size_t)H_DIM * DI;       // [DI][R]
    __bf16* xdbl_bf = dtw_bf  + (size_t)DI * RR;          // [L][96]
    __bf16* y_bf    = xdbl_bf + (size_t)LL * 96;          // [L][DI]
    __bf16* xs_bf   = y_bf    + (size_t)LL * DI;          // [L][DI]
    __bf16* xc_bf   = xs_bf   + (size_t)LL * DI;          // [L][DI]
    __bf16* res_bf  = xc_bf   + (size_t)LL * DI;          // [L][DI]
    __bf16* xpw_pad = res_bf  + (size_t)LL * DI;          // [128][DI]

    const dim3 blk(256);

    // 0) all fp32->bf16 conversions + x_proj weight pad, one kernel
    convert_all_k<<<dim3(CUMT / 1024), blk, 0, stream>>>(
        x, in_w, outw, dtproj_w, xproj_w,
        x_bf, inw_bf, outw_bf, dtw_bf, xpw_pad);

    // 1) x_and_res = x @ in_proj_w^T + b -> bf16 xc | res  [L][2DI]
    gemm_inproj_k<<<dim3((2*DI)/128, LL/64), blk, 0, stream>>>(
        x_bf, inw_bf, in_b, xc_bf, res_bf);

    // 2) xs = silu(conv(xc) + conv_b)                      [L][DI] bf16
    conv_silu_k<<<dim3((LL*DI)/(8*256)), blk, 0, stream>>>(xc_bf, conv_w, conv_b, xs_bf);

    // 3) x_dbl = xs @ x_proj_w^T  (split-K MFMA + reduce)  [L][96] fp32+bf16
    gemm64_bf16_nt<0,0,KSPL,0><<<dim3(1, LL/64, KSPL), blk, 0, stream>>>(
        xs_bf, DI, xpw_pad, DI, nullptr, xpart, 96, 96, (size_t)LL * 96, DI);
    reduce_xdbl_k<<<dim3((LL * 96) / 256), blk, 0, stream>>>(xpart, xdbl, xdbl_bf);

    // 4) delta = softplus(x_dbl[:, :64] @ dt_proj_w^T + b) [L][DI] fp32
    gemm64_bf16_nt<1,1,1,1><<<dim3(DI/128, LL/64), blk, 0, stream>>>(
        xdbl_bf, 96, dtw_bf, RR, dtproj_b, delta, DI, DI, 0, RR);

    // 5-7) chunked scan (NC=64); scan3 emits y as bf16
    scan1_k<<<dim3(DI/256, NC), blk, 0, stream>>>(delta, xs_bf, A_log, xdbl, P, S);
    scan2_k<<<dim3((DI*NS)/256), blk, 0, stream>>>(P, S, Hp);
    scan3_k<<<dim3(DI/256, NC), blk, 0, stream>>>(delta, xs_bf, A_log, xdbl, Hp, res_bf, Dp, y_bf);

    // 8) out = y @ out_proj_w^T  (split-K=2 + reduce)      [L][H]
    gemm64_bf16_nt<0,0,2,1><<<dim3(H_DIM/128, LL/64, 2), blk, 0, stream>>>(
        y_bf, DI, outw_bf, DI, nullptr, opart, H_DIM, H_DIM, (size_t)LL * H_DIM, DI);
    reduce_out_k<<<dim3((LL * H_DIM) / 1024), blk, 0, stream>>>(opart, out);
}